// Round 5
// baseline (647.106 us; speedup 1.0000x reference)
//
#include <hip/hip_runtime.h>
#include <hip/hip_bf16.h>

// GCN layer: h = x@W; symmetric-norm aggregation with self-loops; +b, relu, log_softmax.
// Decomposition: g[i] = (x[i]@W)*dinv[i]; out[c] = LSM(relu(dinv[c]*(g[c]+sum_{e:col=c} g[row_e]) + b))
// Strategy: build CSR by dst (counting sort), then gather-aggregate (no float atomics).
// GEMM: barrier-free per-wave rows; W column cached in registers (128 VGPR/lane, statically
//       indexed -> stays in registers per rule #20); x row staged in wave-private LDS slice.
// Aggregate: 8/4/2/1 unroll ladder -> multiple outstanding 256B wave-coalesced gathers even in tail.

#define IN_CH 128
#define OUT_CH 64
#define NPAD 100352   // N rounded up, used as array stride in workspace

// ---------------- degree count (int): deg[col]++ per edge ----------------
__global__ void count_deg_kernel(const int* __restrict__ cols, int* __restrict__ deg, int E) {
    int i = blockIdx.x * blockDim.x + threadIdx.x;
    if (i < E) atomicAdd(&deg[cols[i]], 1);
}

// ---------------- single-block scan: rowstart/cursor = excl prefix(deg); dinv = rsqrt(deg+1) ----------------
__global__ __launch_bounds__(1024) void scan_kernel(
    const int* __restrict__ deg, int* __restrict__ rowstart, int* __restrict__ cursor,
    float* __restrict__ dinv, int N, int E)
{
    __shared__ int sums[1024];
    const int tid = threadIdx.x;
    const int per = (N + 1023) / 1024;
    const int start = tid * per;
    const int end = min(start + per, N);

    int s = 0;
    for (int i = start; i < end; ++i) s += deg[i];
    sums[tid] = s;
    __syncthreads();
    // Hillis-Steele inclusive scan (read-then-barrier-then-write is race-free)
    for (int off = 1; off < 1024; off <<= 1) {
        int v = 0;
        if (tid >= off) v = sums[tid - off];
        __syncthreads();
        if (tid >= off) sums[tid] += v;
        __syncthreads();
    }
    int run = sums[tid] - s;  // exclusive base for this thread's range
    for (int i = start; i < end; ++i) {
        rowstart[i] = run;
        cursor[i]   = run;
        dinv[i]     = rsqrtf((float)deg[i] + 1.0f);
        run += deg[i];
    }
    if (tid == 0) rowstart[N] = E;
}

// ---------------- CSR fill: csr_src[pos++] = row for each edge (by dst) ----------------
__global__ void fill_csr_kernel(const int* __restrict__ rows, const int* __restrict__ cols,
                                int* __restrict__ cursor, int* __restrict__ csr_src, int E) {
    int i = blockIdx.x * blockDim.x + threadIdx.x;
    if (i < E) {
        int p = atomicAdd(&cursor[cols[i]], 1);
        csr_src[p] = rows[i];
    }
}

// ---------------- g = (x @ W) * dinv ----------------
// Barrier-free: each wave independently owns rows (4 waves/block, wave-private LDS slice).
__global__ __launch_bounds__(256) void gemm_scale_kernel(
    const float* __restrict__ x, const float* __restrict__ W,
    const float* __restrict__ dinv, float* __restrict__ g, int N)
{
    __shared__ float xs[4][IN_CH];           // 2 KB, one 512B slice per wave

    const int wave = threadIdx.x >> 6;
    const int lane = threadIdx.x & 63;

    float Wreg[IN_CH];                       // lane's W column, statically indexed
    #pragma unroll
    for (int k = 0; k < IN_CH; ++k) Wreg[k] = W[k * OUT_CH + lane];

    const int wid    = blockIdx.x * 4 + wave;
    const int stride = gridDim.x * 4;

    for (int r = wid; r < N; r += stride) {
        // stage row r into this wave's LDS slice (coalesced 512B read)
        float2 v = *reinterpret_cast<const float2*>(x + (size_t)r * IN_CH + lane * 2);
        xs[wave][lane * 2]     = v.x;
        xs[wave][lane * 2 + 1] = v.y;
        // compiler inserts lgkmcnt wait for the intra-wave LDS RAW below
        const float4* xv = reinterpret_cast<const float4*>(xs[wave]);
        float sum = 0.f;
        #pragma unroll
        for (int k4 = 0; k4 < IN_CH / 4; ++k4) {
            float4 xk = xv[k4];              // broadcast read (all lanes same addr)
            sum = fmaf(xk.x, Wreg[4 * k4 + 0], sum);
            sum = fmaf(xk.y, Wreg[4 * k4 + 1], sum);
            sum = fmaf(xk.z, Wreg[4 * k4 + 2], sum);
            sum = fmaf(xk.w, Wreg[4 * k4 + 3], sum);
        }
        g[(size_t)r * OUT_CH + lane] = sum * dinv[r];
    }
}

// ---------------- aggregate + finalize (wave per node) ----------------
// acc = g[r] + sum_{j in CSR[r]} g[src_j]; v = acc*dinv[r] + b; relu; log_softmax; write out.
// 8/4/2/1 ladder: keeps multiple independent 256B gathers in flight even for the tail
// (deg ~ Poisson(16): mean tail after 8-way body is ~3.5 edges).
__global__ __launch_bounds__(256) void aggregate_kernel(
    const float* __restrict__ g, const int* __restrict__ rowstart,
    const int* __restrict__ csr_src, const float* __restrict__ dinv,
    const float* __restrict__ b, float* __restrict__ out, int N)
{
    const int r = blockIdx.x * 4 + (threadIdx.x >> 6);   // wave-uniform
    if (r >= N) return;
    const int lane = threadIdx.x & 63;

    const int s0 = rowstart[r];
    const int s1 = rowstart[r + 1];

    float acc = g[(size_t)r * OUT_CH + lane];   // self-loop term
    for (int base = s0; base < s1; base += 64) {
        const int cnt = min(64, s1 - base);
        int src = 0;
        if (lane < cnt) src = csr_src[base + lane];
        int k = 0;
        if (cnt >= 8) {
            float a0 = 0.f, a1 = 0.f, a2 = 0.f, a3 = 0.f;
            float a4 = 0.f, a5 = 0.f, a6 = 0.f, a7 = 0.f;
            for (; k + 8 <= cnt; k += 8) {
                const int i0 = __shfl(src, k + 0), i1 = __shfl(src, k + 1);
                const int i2 = __shfl(src, k + 2), i3 = __shfl(src, k + 3);
                const int i4 = __shfl(src, k + 4), i5 = __shfl(src, k + 5);
                const int i6 = __shfl(src, k + 6), i7 = __shfl(src, k + 7);
                a0 += g[(size_t)i0 * OUT_CH + lane];
                a1 += g[(size_t)i1 * OUT_CH + lane];
                a2 += g[(size_t)i2 * OUT_CH + lane];
                a3 += g[(size_t)i3 * OUT_CH + lane];
                a4 += g[(size_t)i4 * OUT_CH + lane];
                a5 += g[(size_t)i5 * OUT_CH + lane];
                a6 += g[(size_t)i6 * OUT_CH + lane];
                a7 += g[(size_t)i7 * OUT_CH + lane];
            }
            acc += ((a0 + a1) + (a2 + a3)) + ((a4 + a5) + (a6 + a7));
        }
        if (k + 4 <= cnt) {                  // 4-way step: 4 loads in flight
            const int i0 = __shfl(src, k + 0), i1 = __shfl(src, k + 1);
            const int i2 = __shfl(src, k + 2), i3 = __shfl(src, k + 3);
            float a0 = g[(size_t)i0 * OUT_CH + lane];
            float a1 = g[(size_t)i1 * OUT_CH + lane];
            float a2 = g[(size_t)i2 * OUT_CH + lane];
            float a3 = g[(size_t)i3 * OUT_CH + lane];
            acc += (a0 + a1) + (a2 + a3);
            k += 4;
        }
        if (k + 2 <= cnt) {                  // 2-way step: 2 loads in flight
            const int i0 = __shfl(src, k + 0), i1 = __shfl(src, k + 1);
            float a0 = g[(size_t)i0 * OUT_CH + lane];
            float a1 = g[(size_t)i1 * OUT_CH + lane];
            acc += a0 + a1;
            k += 2;
        }
        if (k < cnt)
            acc += g[(size_t)__shfl(src, k) * OUT_CH + lane];
    }

    float v = acc * dinv[r] + b[lane];
    v = fmaxf(v, 0.0f);

    float m = v;
    #pragma unroll
    for (int off = 32; off > 0; off >>= 1) m = fmaxf(m, __shfl_xor(m, off));
    float ex = expf(v - m);
    float s = ex;
    #pragma unroll
    for (int off = 32; off > 0; off >>= 1) s += __shfl_xor(s, off);

    out[(size_t)r * OUT_CH + lane] = v - m - logf(s);
}

// ============ fallback path (small ws): float-atomic scatter ============
__global__ void fb_count_kernel(const int* __restrict__ cols, float* __restrict__ deg, int E) {
    int i = blockIdx.x * blockDim.x + threadIdx.x;
    if (i < E) atomicAdd(&deg[cols[i]], 1.0f);
}
__global__ void fb_dinv_kernel(float* __restrict__ deg, int N) {
    int i = blockIdx.x * blockDim.x + threadIdx.x;
    if (i < N) deg[i] = rsqrtf(deg[i] + 1.0f);
}
__global__ __launch_bounds__(256) void fb_gemm_kernel(
    const float* __restrict__ x, const float* __restrict__ W,
    const float* __restrict__ dinv, float* __restrict__ g, float* __restrict__ acc, int N)
{
    __shared__ float xs[4][IN_CH];
    const int wave = threadIdx.x >> 6;
    const int lane = threadIdx.x & 63;
    float Wreg[IN_CH];
    #pragma unroll
    for (int k = 0; k < IN_CH; ++k) Wreg[k] = W[k * OUT_CH + lane];
    const int wid    = blockIdx.x * 4 + wave;
    const int stride = gridDim.x * 4;
    for (int r = wid; r < N; r += stride) {
        float2 v = *reinterpret_cast<const float2*>(x + (size_t)r * IN_CH + lane * 2);
        xs[wave][lane * 2] = v.x; xs[wave][lane * 2 + 1] = v.y;
        const float4* xv = reinterpret_cast<const float4*>(xs[wave]);
        float sum = 0.f;
        #pragma unroll
        for (int k4 = 0; k4 < IN_CH / 4; ++k4) {
            float4 xk = xv[k4];
            sum = fmaf(xk.x, Wreg[4 * k4 + 0], sum);
            sum = fmaf(xk.y, Wreg[4 * k4 + 1], sum);
            sum = fmaf(xk.z, Wreg[4 * k4 + 2], sum);
            sum = fmaf(xk.w, Wreg[4 * k4 + 3], sum);
        }
        const float gv = sum * dinv[r];
        g[(size_t)r * OUT_CH + lane] = gv;
        acc[(size_t)r * OUT_CH + lane] = gv;
    }
}
__global__ __launch_bounds__(256) void fb_scatter_kernel(
    const int* __restrict__ rows, const int* __restrict__ cols,
    const float* __restrict__ g, float* __restrict__ acc, int E)
{
    const int e = blockIdx.x * 4 + (threadIdx.x >> 6);
    if (e >= E) return;
    const int lane = threadIdx.x & 63;
    atomicAdd(&acc[(size_t)cols[e] * OUT_CH + lane], g[(size_t)rows[e] * OUT_CH + lane]);
}
__global__ __launch_bounds__(256) void fb_finalize_kernel(
    float* __restrict__ acc, const float* __restrict__ dinv, const float* __restrict__ b, int N)
{
    const int r = blockIdx.x * 4 + (threadIdx.x >> 6);
    if (r >= N) return;
    const int lane = threadIdx.x & 63;
    float v = acc[(size_t)r * OUT_CH + lane] * dinv[r] + b[lane];
    v = fmaxf(v, 0.0f);
    float m = v;
    #pragma unroll
    for (int off = 32; off > 0; off >>= 1) m = fmaxf(m, __shfl_xor(m, off));
    float ex = expf(v - m);
    float s = ex;
    #pragma unroll
    for (int off = 32; off > 0; off >>= 1) s += __shfl_xor(s, off);
    acc[(size_t)r * OUT_CH + lane] = v - m - logf(s);
}

extern "C" void kernel_launch(void* const* d_in, const int* in_sizes, int n_in,
                              void* d_out, int out_size, void* d_ws, size_t ws_size,
                              hipStream_t stream) {
    const float* x  = (const float*)d_in[0];
    const int*   ei = (const int*)d_in[1];
    const float* W  = (const float*)d_in[2];
    const float* b  = (const float*)d_in[3];
    float* out = (float*)d_out;

    const int N = in_sizes[0] / IN_CH;       // 100000
    const int E = in_sizes[1] / 2;           // 1600000
    const int* rows = ei;                    // edge_index[0] = src
    const int* cols = ei + E;                // edge_index[1] = dst

    // CSR-path workspace layout (4-byte units):
    //   deg_i[NPAD] | dinv[NPAD] | rowstart[NPAD] | cursor[NPAD] | csr_src[Epad] | g[N*64]
    const size_t Epad = ((size_t)E + 127) & ~(size_t)127;
    const size_t need = ((size_t)NPAD * 4 + Epad + (size_t)N * OUT_CH) * 4;

    if (ws_size >= need) {
        int*   deg      = (int*)d_ws;
        float* dinv     = (float*)d_ws + NPAD;
        int*   rowstart = (int*)d_ws + 2 * NPAD;
        int*   cursor   = (int*)d_ws + 3 * NPAD;
        int*   csr_src  = (int*)d_ws + 4 * NPAD;
        float* g        = (float*)d_ws + 4 * NPAD + Epad;

        hipMemsetAsync(deg, 0, (size_t)N * sizeof(int), stream);
        count_deg_kernel<<<(E + 255) / 256, 256, 0, stream>>>(cols, deg, E);
        scan_kernel<<<1, 1024, 0, stream>>>(deg, rowstart, cursor, dinv, N, E);
        gemm_scale_kernel<<<2048, 256, 0, stream>>>(x, W, dinv, g, N);
        fill_csr_kernel<<<(E + 255) / 256, 256, 0, stream>>>(rows, cols, cursor, csr_src, E);
        aggregate_kernel<<<(N + 3) / 4, 256, 0, stream>>>(g, rowstart, csr_src, dinv, b, out, N);
    } else {
        // fallback: atomic scatter (needs deg[NPAD] + g[N*64] floats)
        float* deg = (float*)d_ws;
        float* g   = (float*)d_ws + NPAD;
        hipMemsetAsync(deg, 0, (size_t)N * sizeof(float), stream);
        fb_count_kernel<<<(E + 255) / 256, 256, 0, stream>>>(cols, deg, E);
        fb_dinv_kernel<<<(N + 255) / 256, 256, 0, stream>>>(deg, N);
        fb_gemm_kernel<<<2048, 256, 0, stream>>>(x, W, deg, g, out, N);
        fb_scatter_kernel<<<(E + 3) / 4, 256, 0, stream>>>(rows, cols, g, out, E);
        fb_finalize_kernel<<<(N + 3) / 4, 256, 0, stream>>>(out, deg, b, N);
    }
}

// Round 6
// 388.448 us; speedup vs baseline: 1.6659x; 1.6659x over previous
//
#include <hip/hip_runtime.h>
#include <hip/hip_bf16.h>

// GCN layer: h = x@W; symmetric-norm aggregation with self-loops; +b, relu, log_softmax.
// Decomposition: g[i] = (x[i]@W)*dinv[i]; out[c] = LSM(relu(dinv[c]*(g[c]+sum_{e:col=c} g[row_e]) + b))
// Strategy: build CSR by dst (counting sort), then gather-aggregate (no float atomics).
// R5 fix: single-block scan (277us, 43% of runtime, occupancy 0.14%) -> 2-kernel
//         hierarchical scan at full grid width (predicted ~13us).

#define IN_CH 128
#define OUT_CH 64
#define NPAD 100352        // N rounded up, used as array stride in workspace
#define SCAN_B 1024        // scan block size
#define MAX_SCAN_BLOCKS 128

// ---------------- degree count (int): deg[col]++ per edge ----------------
__global__ void count_deg_kernel(const int* __restrict__ cols, int* __restrict__ deg, int E) {
    int i = blockIdx.x * blockDim.x + threadIdx.x;
    if (i < E) atomicAdd(&deg[cols[i]], 1);
}

// ---------------- scanA: per-block LDS scan -> partial (local excl prefix) + blocksum ----------------
__global__ __launch_bounds__(SCAN_B) void scanA_kernel(
    const int* __restrict__ deg, int* __restrict__ partial, int* __restrict__ blocksum, int N)
{
    __shared__ int sdata[SCAN_B];
    const int tid = threadIdx.x;
    const int i = blockIdx.x * SCAN_B + tid;

    const int v = (i < N) ? deg[i] : 0;
    sdata[tid] = v;
    __syncthreads();
    // Hillis-Steele inclusive scan (read-then-barrier-then-write is race-free)
    for (int off = 1; off < SCAN_B; off <<= 1) {
        int t = 0;
        if (tid >= off) t = sdata[tid - off];
        __syncthreads();
        sdata[tid] += t;
        __syncthreads();
    }
    if (i < N) partial[i] = sdata[tid] - v;          // local exclusive prefix
    if (tid == SCAN_B - 1) blocksum[blockIdx.x] = sdata[tid];
}

// ---------------- scanC: add block offset; write rowstart/cursor/dinv ----------------
__global__ __launch_bounds__(SCAN_B) void scanC_kernel(
    const int* __restrict__ deg, const int* __restrict__ partial,
    const int* __restrict__ blocksum, int* __restrict__ rowstart,
    int* __restrict__ cursor, float* __restrict__ dinv, int N, int E, int NB)
{
    __shared__ int bs[MAX_SCAN_BLOCKS];
    const int tid = threadIdx.x;
    const int i = blockIdx.x * SCAN_B + tid;

    if (tid < MAX_SCAN_BLOCKS)
        bs[tid] = (tid < blockIdx.x && tid < NB) ? blocksum[tid] : 0;
    __syncthreads();
    for (int off = MAX_SCAN_BLOCKS / 2; off > 0; off >>= 1) {
        if (tid < off) bs[tid] += bs[tid + off];
        __syncthreads();
    }
    const int offset = bs[0];

    if (i < N) {
        const int run = offset + partial[i];
        rowstart[i] = run;
        cursor[i]   = run;
        dinv[i]     = rsqrtf((float)deg[i] + 1.0f);
    }
    if (i == N) rowstart[N] = E;
}

// ---------------- CSR fill: csr_src[pos++] = row for each edge (by dst) ----------------
__global__ void fill_csr_kernel(const int* __restrict__ rows, const int* __restrict__ cols,
                                int* __restrict__ cursor, int* __restrict__ csr_src, int E) {
    int i = blockIdx.x * blockDim.x + threadIdx.x;
    if (i < E) {
        int p = atomicAdd(&cursor[cols[i]], 1);
        csr_src[p] = rows[i];
    }
}

// ---------------- g = (x @ W) * dinv ----------------
// Barrier-free: each wave independently owns rows (4 waves/block, wave-private LDS slice).
__global__ __launch_bounds__(256) void gemm_scale_kernel(
    const float* __restrict__ x, const float* __restrict__ W,
    const float* __restrict__ dinv, float* __restrict__ g, int N)
{
    __shared__ float xs[4][IN_CH];           // 2 KB, one 512B slice per wave

    const int wave = threadIdx.x >> 6;
    const int lane = threadIdx.x & 63;

    float Wreg[IN_CH];                       // lane's W column, statically indexed
    #pragma unroll
    for (int k = 0; k < IN_CH; ++k) Wreg[k] = W[k * OUT_CH + lane];

    const int wid    = blockIdx.x * 4 + wave;
    const int stride = gridDim.x * 4;

    for (int r = wid; r < N; r += stride) {
        // stage row r into this wave's LDS slice (coalesced 512B read)
        float2 v = *reinterpret_cast<const float2*>(x + (size_t)r * IN_CH + lane * 2);
        xs[wave][lane * 2]     = v.x;
        xs[wave][lane * 2 + 1] = v.y;
        // compiler inserts lgkmcnt wait for the intra-wave LDS RAW below
        const float4* xv = reinterpret_cast<const float4*>(xs[wave]);
        float sum = 0.f;
        #pragma unroll
        for (int k4 = 0; k4 < IN_CH / 4; ++k4) {
            float4 xk = xv[k4];              // broadcast read (all lanes same addr)
            sum = fmaf(xk.x, Wreg[4 * k4 + 0], sum);
            sum = fmaf(xk.y, Wreg[4 * k4 + 1], sum);
            sum = fmaf(xk.z, Wreg[4 * k4 + 2], sum);
            sum = fmaf(xk.w, Wreg[4 * k4 + 3], sum);
        }
        g[(size_t)r * OUT_CH + lane] = sum * dinv[r];
    }
}

// ---------------- aggregate + finalize (wave per node) ----------------
// acc = g[r] + sum_{j in CSR[r]} g[src_j]; v = acc*dinv[r] + b; relu; log_softmax; write out.
// 8/4/2/1 ladder: keeps multiple independent 256B gathers in flight even for the tail.
__global__ __launch_bounds__(256) void aggregate_kernel(
    const float* __restrict__ g, const int* __restrict__ rowstart,
    const int* __restrict__ csr_src, const float* __restrict__ dinv,
    const float* __restrict__ b, float* __restrict__ out, int N)
{
    const int r = blockIdx.x * 4 + (threadIdx.x >> 6);   // wave-uniform
    if (r >= N) return;
    const int lane = threadIdx.x & 63;

    const int s0 = rowstart[r];
    const int s1 = rowstart[r + 1];

    float acc = g[(size_t)r * OUT_CH + lane];   // self-loop term
    for (int base = s0; base < s1; base += 64) {
        const int cnt = min(64, s1 - base);
        int src = 0;
        if (lane < cnt) src = csr_src[base + lane];
        int k = 0;
        if (cnt >= 8) {
            float a0 = 0.f, a1 = 0.f, a2 = 0.f, a3 = 0.f;
            float a4 = 0.f, a5 = 0.f, a6 = 0.f, a7 = 0.f;
            for (; k + 8 <= cnt; k += 8) {
                const int i0 = __shfl(src, k + 0), i1 = __shfl(src, k + 1);
                const int i2 = __shfl(src, k + 2), i3 = __shfl(src, k + 3);
                const int i4 = __shfl(src, k + 4), i5 = __shfl(src, k + 5);
                const int i6 = __shfl(src, k + 6), i7 = __shfl(src, k + 7);
                a0 += g[(size_t)i0 * OUT_CH + lane];
                a1 += g[(size_t)i1 * OUT_CH + lane];
                a2 += g[(size_t)i2 * OUT_CH + lane];
                a3 += g[(size_t)i3 * OUT_CH + lane];
                a4 += g[(size_t)i4 * OUT_CH + lane];
                a5 += g[(size_t)i5 * OUT_CH + lane];
                a6 += g[(size_t)i6 * OUT_CH + lane];
                a7 += g[(size_t)i7 * OUT_CH + lane];
            }
            acc += ((a0 + a1) + (a2 + a3)) + ((a4 + a5) + (a6 + a7));
        }
        if (k + 4 <= cnt) {
            const int i0 = __shfl(src, k + 0), i1 = __shfl(src, k + 1);
            const int i2 = __shfl(src, k + 2), i3 = __shfl(src, k + 3);
            float a0 = g[(size_t)i0 * OUT_CH + lane];
            float a1 = g[(size_t)i1 * OUT_CH + lane];
            float a2 = g[(size_t)i2 * OUT_CH + lane];
            float a3 = g[(size_t)i3 * OUT_CH + lane];
            acc += (a0 + a1) + (a2 + a3);
            k += 4;
        }
        if (k + 2 <= cnt) {
            const int i0 = __shfl(src, k + 0), i1 = __shfl(src, k + 1);
            float a0 = g[(size_t)i0 * OUT_CH + lane];
            float a1 = g[(size_t)i1 * OUT_CH + lane];
            acc += a0 + a1;
            k += 2;
        }
        if (k < cnt)
            acc += g[(size_t)__shfl(src, k) * OUT_CH + lane];
    }

    float v = acc * dinv[r] + b[lane];
    v = fmaxf(v, 0.0f);

    float m = v;
    #pragma unroll
    for (int off = 32; off > 0; off >>= 1) m = fmaxf(m, __shfl_xor(m, off));
    float ex = expf(v - m);
    float s = ex;
    #pragma unroll
    for (int off = 32; off > 0; off >>= 1) s += __shfl_xor(s, off);

    out[(size_t)r * OUT_CH + lane] = v - m - logf(s);
}

// ============ fallback path (small ws): float-atomic scatter ============
__global__ void fb_count_kernel(const int* __restrict__ cols, float* __restrict__ deg, int E) {
    int i = blockIdx.x * blockDim.x + threadIdx.x;
    if (i < E) atomicAdd(&deg[cols[i]], 1.0f);
}
__global__ void fb_dinv_kernel(float* __restrict__ deg, int N) {
    int i = blockIdx.x * blockDim.x + threadIdx.x;
    if (i < N) deg[i] = rsqrtf(deg[i] + 1.0f);
}
__global__ __launch_bounds__(256) void fb_gemm_kernel(
    const float* __restrict__ x, const float* __restrict__ W,
    const float* __restrict__ dinv, float* __restrict__ g, float* __restrict__ acc, int N)
{
    __shared__ float xs[4][IN_CH];
    const int wave = threadIdx.x >> 6;
    const int lane = threadIdx.x & 63;
    float Wreg[IN_CH];
    #pragma unroll
    for (int k = 0; k < IN_CH; ++k) Wreg[k] = W[k * OUT_CH + lane];
    const int wid    = blockIdx.x * 4 + wave;
    const int stride = gridDim.x * 4;
    for (int r = wid; r < N; r += stride) {
        float2 v = *reinterpret_cast<const float2*>(x + (size_t)r * IN_CH + lane * 2);
        xs[wave][lane * 2] = v.x; xs[wave][lane * 2 + 1] = v.y;
        const float4* xv = reinterpret_cast<const float4*>(xs[wave]);
        float sum = 0.f;
        #pragma unroll
        for (int k4 = 0; k4 < IN_CH / 4; ++k4) {
            float4 xk = xv[k4];
            sum = fmaf(xk.x, Wreg[4 * k4 + 0], sum);
            sum = fmaf(xk.y, Wreg[4 * k4 + 1], sum);
            sum = fmaf(xk.z, Wreg[4 * k4 + 2], sum);
            sum = fmaf(xk.w, Wreg[4 * k4 + 3], sum);
        }
        const float gv = sum * dinv[r];
        g[(size_t)r * OUT_CH + lane] = gv;
        acc[(size_t)r * OUT_CH + lane] = gv;
    }
}
__global__ __launch_bounds__(256) void fb_scatter_kernel(
    const int* __restrict__ rows, const int* __restrict__ cols,
    const float* __restrict__ g, float* __restrict__ acc, int E)
{
    const int e = blockIdx.x * 4 + (threadIdx.x >> 6);
    if (e >= E) return;
    const int lane = threadIdx.x & 63;
    atomicAdd(&acc[(size_t)cols[e] * OUT_CH + lane], g[(size_t)rows[e] * OUT_CH + lane]);
}
__global__ __launch_bounds__(256) void fb_finalize_kernel(
    float* __restrict__ acc, const float* __restrict__ dinv, const float* __restrict__ b, int N)
{
    const int r = blockIdx.x * 4 + (threadIdx.x >> 6);
    if (r >= N) return;
    const int lane = threadIdx.x & 63;
    float v = acc[(size_t)r * OUT_CH + lane] * dinv[r] + b[lane];
    v = fmaxf(v, 0.0f);
    float m = v;
    #pragma unroll
    for (int off = 32; off > 0; off >>= 1) m = fmaxf(m, __shfl_xor(m, off));
    float ex = expf(v - m);
    float s = ex;
    #pragma unroll
    for (int off = 32; off > 0; off >>= 1) s += __shfl_xor(s, off);
    acc[(size_t)r * OUT_CH + lane] = v - m - logf(s);
}

extern "C" void kernel_launch(void* const* d_in, const int* in_sizes, int n_in,
                              void* d_out, int out_size, void* d_ws, size_t ws_size,
                              hipStream_t stream) {
    const float* x  = (const float*)d_in[0];
    const int*   ei = (const int*)d_in[1];
    const float* W  = (const float*)d_in[2];
    const float* b  = (const float*)d_in[3];
    float* out = (float*)d_out;

    const int N = in_sizes[0] / IN_CH;       // 100000
    const int E = in_sizes[1] / 2;           // 1600000
    const int* rows = ei;                    // edge_index[0] = src
    const int* cols = ei + E;                // edge_index[1] = dst
    const int NB = (N + SCAN_B - 1) / SCAN_B;  // 98 scan blocks

    // CSR-path workspace layout (4-byte units):
    //   deg_i[NPAD] | dinv[NPAD] | rowstart[NPAD] | cursor[NPAD] | partial[NPAD] |
    //   blocksum[MAX_SCAN_BLOCKS] | csr_src[Epad] | g[N*64]
    const size_t Epad = ((size_t)E + 127) & ~(size_t)127;
    const size_t need = ((size_t)NPAD * 5 + MAX_SCAN_BLOCKS + Epad + (size_t)N * OUT_CH) * 4;

    if (ws_size >= need) {
        int*   deg      = (int*)d_ws;
        float* dinv     = (float*)d_ws + NPAD;
        int*   rowstart = (int*)d_ws + 2 * NPAD;
        int*   cursor   = (int*)d_ws + 3 * NPAD;
        int*   partial  = (int*)d_ws + 4 * NPAD;
        int*   blocksum = (int*)d_ws + 5 * NPAD;
        int*   csr_src  = (int*)d_ws + 5 * NPAD + MAX_SCAN_BLOCKS;
        float* g        = (float*)d_ws + 5 * NPAD + MAX_SCAN_BLOCKS + Epad;

        hipMemsetAsync(deg, 0, (size_t)N * sizeof(int), stream);
        count_deg_kernel<<<(E + 255) / 256, 256, 0, stream>>>(cols, deg, E);
        scanA_kernel<<<NB, SCAN_B, 0, stream>>>(deg, partial, blocksum, N);
        scanC_kernel<<<NB, SCAN_B, 0, stream>>>(deg, partial, blocksum, rowstart, cursor, dinv, N, E, NB);
        gemm_scale_kernel<<<2048, 256, 0, stream>>>(x, W, dinv, g, N);
        fill_csr_kernel<<<(E + 255) / 256, 256, 0, stream>>>(rows, cols, cursor, csr_src, E);
        aggregate_kernel<<<(N + 3) / 4, 256, 0, stream>>>(g, rowstart, csr_src, dinv, b, out, N);
    } else {
        // fallback: atomic scatter (needs deg[NPAD] + g[N*64] floats)
        float* deg = (float*)d_ws;
        float* g   = (float*)d_ws + NPAD;
        hipMemsetAsync(deg, 0, (size_t)N * sizeof(float), stream);
        fb_count_kernel<<<(E + 255) / 256, 256, 0, stream>>>(cols, deg, E);
        fb_dinv_kernel<<<(N + 255) / 256, 256, 0, stream>>>(deg, N);
        fb_gemm_kernel<<<2048, 256, 0, stream>>>(x, W, deg, g, out, N);
        fb_scatter_kernel<<<(E + 3) / 4, 256, 0, stream>>>(rows, cols, g, out, E);
        fb_finalize_kernel<<<(N + 3) / 4, 256, 0, stream>>>(out, deg, b, N);
    }
}